// Round 1
// baseline (822.967 us; speedup 1.0000x reference)
//
#include <hip/hip_runtime.h>

typedef unsigned short u16;
typedef __bf16  bf16x8 __attribute__((ext_vector_type(8)));
typedef float   f32x4  __attribute__((ext_vector_type(4)));

#define N_ROWS 1500000
#define S_SEG  16384
#define ROWS_PB 32          // 1.5M / 32 = 46875 exactly -> no tail handling

// hardware RNE f32->bf16 (compiler emits v_cvt_pk_bf16_f32 on gfx950)
__device__ __forceinline__ u16 f2bf(float f) {
    union { __bf16 h; u16 u; } cv;
    cv.h = (__bf16)f;
    return cv.u;
}

// ---------------- zero the fp32 segment accumulators ----------------
__global__ void zero_ws_kernel(float* p, int n4) {
    int i = blockIdx.x * 256 + threadIdx.x;
    if (i < n4) reinterpret_cast<float4*>(p)[i] = make_float4(0.f, 0.f, 0.f, 0.f);
}

// ------- transpose + fp32->bf16 convert the 4 big-GEMM weight matrices -------
__global__ void transpose_weights(const float* __restrict__ w0, const float* __restrict__ w1,
                                  const float* __restrict__ r0, const float* __restrict__ r1,
                                  u16* __restrict__ w0T, u16* __restrict__ w1T,
                                  u16* __restrict__ r0T, u16* __restrict__ r1T) {
    int idx = blockIdx.x * 256 + threadIdx.x;     // 0 .. 24576
    if (idx < 8192) {
        int o = idx >> 6, k = idx & 63;
        w0T[o * 64 + k] = f2bf(w0[k * 128 + o]);
    } else if (idx < 12288) {
        int t = idx - 8192; int o = t >> 7, k = t & 127;
        w1T[o * 128 + k] = f2bf(w1[k * 32 + o]);
    } else if (idx < 20480) {
        int t = idx - 12288; int o = t >> 6, k = t & 63;
        r0T[o * 64 + k] = f2bf(r0[k * 128 + o]);
    } else if (idx < 24576) {
        int t = idx - 20480; int o = t >> 7, k = t & 127;
        r1T[o * 128 + k] = f2bf(r1[k * 32 + o]);
    }
}

// ---------------- main: per-row 2-layer MLP x2 branches + segment atomics ----------------
// 32 rows/block, 4 waves, MFMA 16x16x32 bf16.
// A-frag: A[m=lane&15][k=(lane>>4)*8+j];  B-frag: B[k=(lane>>4)*8+j][n=lane&15]
// C/D   : col=lane&15, row=(lane>>4)*4+reg
// LDS: xs 4608 + h1s 8704 + h2s 8448 + ids 128 + sred 1024 = 22912 B -> 7 blocks/CU.
#define XS_LD 72
#define H1_LD 136
#define H2B_LD 66   // 64 cols (tfc 0-31 | rl 32-63) + 2 pad, fp32

__global__ __launch_bounds__(256) void main_mlp_seg(
    const float* __restrict__ x, const int* __restrict__ seg_ids,
    const u16* __restrict__ w0T, const float* __restrict__ b0a,
    const u16* __restrict__ w1T, const float* __restrict__ b1a,
    const u16* __restrict__ r0T, const float* __restrict__ rb0,
    const u16* __restrict__ r1T, const float* __restrict__ rb1,
    float* __restrict__ seg_out, float* __restrict__ rseg_out)
{
    __shared__ u16   xs [ROWS_PB * XS_LD];
    __shared__ u16   h1s[ROWS_PB * H1_LD];
    __shared__ float h2s[ROWS_PB * H2B_LD];
    __shared__ int   s_ids[ROWS_PB];
    __shared__ float sred[256];          // cross-group scratch for uniform-segment fast path

    const int tid = threadIdx.x;
    const int i0  = blockIdx.x * ROWS_PB;

    if (tid < ROWS_PB) s_ids[tid] = seg_ids[i0 + tid];

    // stage x tile: 32 rows x 64 fp32 -> bf16 in LDS (coalesced float4, 2/thread)
    #pragma unroll
    for (int j = 0; j < 2; ++j) {
        int ch = tid + j * 256;          // 0..511
        int r = ch >> 4, c4 = ch & 15;   // 16 float4 per row
        float4 v = *reinterpret_cast<const float4*>(x + (size_t)(i0 + r) * 64 + c4 * 4);
        ushort4 pk;
        pk.x = f2bf(v.x); pk.y = f2bf(v.y); pk.z = f2bf(v.z); pk.w = f2bf(v.w);
        *reinterpret_cast<ushort4*>(&xs[r * XS_LD + c4 * 4]) = pk;
    }
    __syncthreads();

    const int wid = tid >> 6, lane = tid & 63;
    const int m = lane & 15, q = lane >> 4;

    #pragma unroll 1
    for (int br = 0; br < 2; ++br) {
        const u16*   W0 = br ? r0T : w0T;
        const float* B0 = br ? rb0 : b0a;
        const u16*   W1 = br ? r1T : w1T;
        const float* B1 = br ? rb1 : b1a;

        // ---- GEMM1: [32,64] @ [64,128] -> relu -> h1s (bf16) ----
        // wave `wid` owns col-tiles {2*wid, 2*wid+1}, loops 2 row-tiles
        bf16x8 bf[2][2];
        float bias0v[2];
        #pragma unroll
        for (int ct = 0; ct < 2; ++ct) {
            int n0 = (2 * wid + ct) * 16;
            #pragma unroll
            for (int ks = 0; ks < 2; ++ks)
                bf[ct][ks] = *reinterpret_cast<const bf16x8*>(W0 + (n0 + m) * 64 + ks * 32 + q * 8);
            bias0v[ct] = B0[n0 + m];
        }
        #pragma unroll
        for (int rt = 0; rt < 2; ++rt) {
            bf16x8 a0 = *reinterpret_cast<const bf16x8*>(&xs[(rt * 16 + m) * XS_LD + 0  + q * 8]);
            bf16x8 a1 = *reinterpret_cast<const bf16x8*>(&xs[(rt * 16 + m) * XS_LD + 32 + q * 8]);
            #pragma unroll
            for (int ct = 0; ct < 2; ++ct) {
                f32x4 acc = {0.f, 0.f, 0.f, 0.f};
                acc = __builtin_amdgcn_mfma_f32_16x16x32_bf16(a0, bf[ct][0], acc, 0, 0, 0);
                acc = __builtin_amdgcn_mfma_f32_16x16x32_bf16(a1, bf[ct][1], acc, 0, 0, 0);
                int colg = (2 * wid + ct) * 16 + m;
                #pragma unroll
                for (int i = 0; i < 4; ++i) {
                    float v = fmaxf(acc[i] + bias0v[ct], 0.f);
                    h1s[(rt * 16 + q * 4 + i) * H1_LD + colg] = f2bf(v);
                }
            }
        }
        __syncthreads();

        // ---- GEMM2: [32,128] @ [128,32] -> relu -> h2s[., br*32+c] (fp32) ----
        // 4 output tiles (2 rt x 2 ct); wave w owns (rt=w&1, ct=w>>1)
        {
            int rt = wid & 1, ct = wid >> 1;
            float bias1v = B1[ct * 16 + m];
            bf16x8 a[4], bg[4];
            #pragma unroll
            for (int ks = 0; ks < 4; ++ks) {
                bg[ks] = *reinterpret_cast<const bf16x8*>(W1 + (ct * 16 + m) * 128 + ks * 32 + q * 8);
                a[ks]  = *reinterpret_cast<const bf16x8*>(&h1s[(rt * 16 + m) * H1_LD + ks * 32 + q * 8]);
            }
            f32x4 acc = {0.f, 0.f, 0.f, 0.f};
            #pragma unroll
            for (int ks = 0; ks < 4; ++ks)
                acc = __builtin_amdgcn_mfma_f32_16x16x32_bf16(a[ks], bg[ks], acc, 0, 0, 0);
            int colg = br * 32 + ct * 16 + m;
            #pragma unroll
            for (int i = 0; i < 4; ++i) {
                float v = fmaxf(acc[i] + bias1v, 0.f);
                h2s[(rt * 16 + q * 4 + i) * H2B_LD + colg] = v;
            }
        }
        __syncthreads();   // h2s half ready; also protects h1s for next branch
    }

    // ---- sorted-run segment accumulate, both branches at once ----
    // thread = (c in [0,64), 8-row group g in [0,4)); cols 0-31 tfc, 32-63 rl
    {
        int c = tid & 63, g = tid >> 6;
        float* sp  = (c < 32) ? seg_out : rseg_out;
        int    col = c & 31;
        if (s_ids[0] == s_ids[ROWS_PB - 1]) {
            // fast path: whole block in one segment (sorted ids) -> 1 atomic/col
            float a = 0.f;
            #pragma unroll
            for (int r = 0; r < 8; ++r)
                a += h2s[(g * 8 + r) * H2B_LD + c];
            sred[g * 64 + c] = a;
            __syncthreads();
            if (g == 0) {
                float t = sred[c] + sred[64 + c] + sred[128 + c] + sred[192 + c];
                atomicAdd(&sp[s_ids[0] * 32 + col], t);
            }
        } else {
            int cur = -1; float acc = 0.f;
            #pragma unroll
            for (int r = 0; r < 8; ++r) {
                int rr = g * 8 + r;
                int id = s_ids[rr];
                if (id != cur) {
                    if (cur >= 0) atomicAdd(&sp[cur * 32 + col], acc);
                    cur = id; acc = 0.f;
                }
                acc += h2s[rr * H2B_LD + c];
            }
            if (cur >= 0) atomicAdd(&sp[cur * 32 + col], acc);
        }
    }
}

// ---------------- per-segment heads + cost MLP + policy (fp32 in, fp32 out) ----------------
__global__ __launch_bounds__(256) void heads_kernel(
    const float* __restrict__ seg, const float* __restrict__ rseg,
    const float* __restrict__ fwd0_w, const float* __restrict__ fwd0_b,
    const float* __restrict__ fwd1_w, const float* __restrict__ fwd1_b,
    const float* __restrict__ com0_w, const float* __restrict__ com0_b,
    const float* __restrict__ com1_w, const float* __restrict__ com1_b,
    const float* __restrict__ bwd0_w, const float* __restrict__ bwd0_b,
    const float* __restrict__ bwd1_w, const float* __restrict__ bwd1_b,
    const float* __restrict__ cost0_w, const float* __restrict__ cost0_b,
    const float* __restrict__ cost1_w, const float* __restrict__ cost1_b,
    const float* __restrict__ pol_w, const float* __restrict__ pol_b,
    float* __restrict__ out)
{
    __shared__ float s_seg[4][32];
    __shared__ float s_rseg[4][32];
    __shared__ float s_c0[4][64];
    const int tid = threadIdx.x, wid = tid >> 6, lane = tid & 63;
    const int s = blockIdx.x * 4 + wid;

    if (lane < 32) {
        s_seg[wid][lane]  = seg[s * 32 + lane];
        s_rseg[wid][lane] = rseg[s * 32 + lane];
    }
    __syncthreads();

    const float* w0s[3] = {fwd0_w, com0_w, bwd0_w};
    const float* b0s[3] = {fwd0_b, com0_b, bwd0_b};
    const float* w1s[3] = {fwd1_w, com1_w, bwd1_w};
    const float* b1s[3] = {fwd1_b, com1_b, bwd1_b};
    float costs[3];
    #pragma unroll
    for (int hh = 0; hh < 3; ++hh) {
        float t = 0.f;
        #pragma unroll
        for (int k = 0; k < 32; ++k)
            t = fmaf(s_seg[wid][k], w0s[hh][k * 64 + lane], t);
        t = fmaxf(t + b0s[hh][lane], 0.f);
        float red = t * w1s[hh][lane];
        red += __shfl_down(red, 32);
        red += __shfl_down(red, 16);
        red += __shfl_down(red, 8);
        red += __shfl_down(red, 4);
        red += __shfl_down(red, 2);
        red += __shfl_down(red, 1);
        costs[hh] = __shfl(red, 0) + b1s[hh][0];
    }

    float c0 = costs[0] * cost0_w[lane] +
               costs[1] * cost0_w[64 + lane] +
               costs[2] * cost0_w[128 + lane] + cost0_b[lane];
    c0 = fmaxf(c0, 0.f);
    s_c0[wid][lane] = c0;
    __syncthreads();

    int kk = lane & 31;
    float c1 = 0.f;
    #pragma unroll 8
    for (int j = 0; j < 64; ++j)
        c1 = fmaf(s_c0[wid][j], cost1_w[j * 32 + kk], c1);
    c1 = fmaxf(c1 + cost1_b[kk], 0.f);

    float p = 0.f;
    if (lane < 32)
        p = s_rseg[wid][lane] * pol_w[lane] + c1 * pol_w[32 + lane];
    p += __shfl_down(p, 32);
    p += __shfl_down(p, 16);
    p += __shfl_down(p, 8);
    p += __shfl_down(p, 4);
    p += __shfl_down(p, 2);
    p += __shfl_down(p, 1);
    if (lane == 0) out[s] = p + pol_b[0];    // fp32 output
}

extern "C" void kernel_launch(void* const* d_in, const int* in_sizes, int n_in,
                              void* d_out, int out_size, void* d_ws, size_t ws_size,
                              hipStream_t stream) {
    const float* x       = (const float*)d_in[0];
    const int*   seg_ids = (const int*)d_in[1];
    const float* tfc0_w = (const float*)d_in[4];
    const float* tfc0_b = (const float*)d_in[5];
    const float* tfc1_w = (const float*)d_in[6];
    const float* tfc1_b = (const float*)d_in[7];
    const float* fwd0_w = (const float*)d_in[8];
    const float* fwd0_b = (const float*)d_in[9];
    const float* fwd1_w = (const float*)d_in[10];
    const float* fwd1_b = (const float*)d_in[11];
    const float* com0_w = (const float*)d_in[12];
    const float* com0_b = (const float*)d_in[13];
    const float* com1_w = (const float*)d_in[14];
    const float* com1_b = (const float*)d_in[15];
    const float* bwd0_w = (const float*)d_in[16];
    const float* bwd0_b = (const float*)d_in[17];
    const float* bwd1_w = (const float*)d_in[18];
    const float* bwd1_b = (const float*)d_in[19];
    const float* rl0_w  = (const float*)d_in[20];
    const float* rl0_b  = (const float*)d_in[21];
    const float* rl1_w  = (const float*)d_in[22];
    const float* rl1_b  = (const float*)d_in[23];
    const float* cost0_w = (const float*)d_in[24];
    const float* cost0_b = (const float*)d_in[25];
    const float* cost1_w = (const float*)d_in[26];
    const float* cost1_b = (const float*)d_in[27];
    const float* pol_w   = (const float*)d_in[28];
    const float* pol_b   = (const float*)d_in[29];

    char* ws = (char*)d_ws;
    const size_t seg_bytes = (size_t)S_SEG * 32 * sizeof(float);   // 2 MB each
    float* seg  = (float*)ws;
    float* rseg = (float*)(ws + seg_bytes);
    u16* w0T = (u16*)(ws + 2 * seg_bytes);
    u16* w1T = w0T + 128 * 64;
    u16* r0T = w1T + 32 * 128;
    u16* r1T = r0T + 128 * 64;

    int n4 = (int)(2 * seg_bytes / 16);
    zero_ws_kernel<<<(n4 + 255) / 256, 256, 0, stream>>>(seg, n4);
    transpose_weights<<<96, 256, 0, stream>>>(tfc0_w, tfc1_w, rl0_w, rl1_w,
                                              w0T, w1T, r0T, r1T);
    main_mlp_seg<<<N_ROWS / ROWS_PB, 256, 0, stream>>>(
        x, seg_ids, w0T, tfc0_b, w1T, tfc1_b, r0T, rl0_b, r1T, rl1_b, seg, rseg);
    heads_kernel<<<S_SEG / 4, 256, 0, stream>>>(
        seg, rseg,
        fwd0_w, fwd0_b, fwd1_w, fwd1_b,
        com0_w, com0_b, com1_w, com1_b,
        bwd0_w, bwd0_b, bwd1_w, bwd1_b,
        cost0_w, cost0_b, cost1_w, cost1_b,
        pol_w, pol_b, (float*)d_out);
}

// Round 3
// 693.455 us; speedup vs baseline: 1.1868x; 1.1868x over previous
//
#include <hip/hip_runtime.h>

typedef unsigned short u16;
typedef __bf16  bf16x8 __attribute__((ext_vector_type(8)));
typedef float   f32x4  __attribute__((ext_vector_type(4)));

#define N_ROWS 1500000
#define S_SEG  16384
#define ROWS_PB 32
#define TILES_PB 15
#define GRID_MAIN 3125      // 3125 * 15 * 32 = 1,500,000 exactly

#define XS_LD  72           // 64 bf16 cols + 8 pad
#define H1B_LD 264          // 256 cols (br0: 0-127 | br1: 128-255) + 8 pad, bf16
#define H2B_LD 66           // 64 cols (tfc 0-31 | rl 32-63) + 2 pad, fp32

// hardware RNE f32->bf16 (v_cvt_pk_bf16_f32 on gfx950)
__device__ __forceinline__ u16 f2bf(float f) {
    union { __bf16 h; u16 u; } cv;
    cv.h = (__bf16)f;
    return cv.u;
}

// ---------------- zero the fp32 segment accumulators ----------------
__global__ void zero_ws_kernel(float* p, int n4) {
    int i = blockIdx.x * 256 + threadIdx.x;
    if (i < n4) reinterpret_cast<float4*>(p)[i] = make_float4(0.f, 0.f, 0.f, 0.f);
}

// ------- transpose + fp32->bf16 convert the 4 big-GEMM weight matrices -------
__global__ void transpose_weights(const float* __restrict__ w0, const float* __restrict__ w1,
                                  const float* __restrict__ r0, const float* __restrict__ r1,
                                  u16* __restrict__ w0T, u16* __restrict__ w1T,
                                  u16* __restrict__ r0T, u16* __restrict__ r1T) {
    int idx = blockIdx.x * 256 + threadIdx.x;     // 0 .. 24576
    if (idx < 8192) {
        int o = idx >> 6, k = idx & 63;
        w0T[o * 64 + k] = f2bf(w0[k * 128 + o]);
    } else if (idx < 12288) {
        int t = idx - 8192; int o = t >> 7, k = t & 127;
        w1T[o * 128 + k] = f2bf(w1[k * 32 + o]);
    } else if (idx < 20480) {
        int t = idx - 12288; int o = t >> 6, k = t & 63;
        r0T[o * 64 + k] = f2bf(r0[k * 128 + o]);
    } else if (idx < 24576) {
        int t = idx - 20480; int o = t >> 7, k = t & 127;
        r1T[o * 128 + k] = f2bf(r1[k * 32 + o]);
    }
}

// ---------------- main: persistent 15-tile blocks, fused branches, 3 barriers/tile ----------------
// MFMA 16x16x32 bf16. A-frag: A[m=lane&15][k=q*8+j]; B-frag: B[k=q*8+j][n=lane&15]
// C/D: col=lane&15, row=q*4+reg.
// LDS: xs dbl 9216 + h1s 16896 + h2s 8448 + ids 256 + sred 1024 = 35840 B -> 4 blocks/CU.
__global__ __launch_bounds__(256, 4) void main_mlp_seg(
    const float* __restrict__ x, const int* __restrict__ seg_ids,
    const u16* __restrict__ w0T, const float* __restrict__ b0a,
    const u16* __restrict__ w1T, const float* __restrict__ b1a,
    const u16* __restrict__ r0T, const float* __restrict__ rb0,
    const u16* __restrict__ r1T, const float* __restrict__ rb1,
    float* __restrict__ seg_out, float* __restrict__ rseg_out)
{
    __shared__ u16   xs [2][ROWS_PB * XS_LD];
    __shared__ u16   h1s[ROWS_PB * H1B_LD];
    __shared__ float h2s[ROWS_PB * H2B_LD];
    __shared__ int   s_ids[2][ROWS_PB];
    __shared__ float sred[256];

    const int tid  = threadIdx.x;
    const int wid  = tid >> 6, lane = tid & 63;
    const int m = lane & 15, q = lane >> 4;
    const size_t row0 = (size_t)blockIdx.x * (TILES_PB * ROWS_PB);

    // ---- hoist all GEMM weights + biases into registers (loop-invariant) ----
    bf16x8 wA[2][2][2];     // [br][ct][ks] GEMM1, this wave's col-tiles {2w,2w+1}
    float  bz0[2][2];
    #pragma unroll
    for (int br = 0; br < 2; ++br) {
        const u16*   W0 = br ? r0T : w0T;
        const float* B0 = br ? rb0 : b0a;
        #pragma unroll
        for (int ct = 0; ct < 2; ++ct) {
            int n0 = (2 * wid + ct) * 16;
            #pragma unroll
            for (int ks = 0; ks < 2; ++ks)
                wA[br][ct][ks] = *reinterpret_cast<const bf16x8*>(W0 + (n0 + m) * 64 + ks * 32 + q * 8);
            bz0[br][ct] = B0[n0 + m];
        }
    }
    const int brw = wid >> 1, rtw = wid & 1;     // GEMM2: wave -> (branch, row-tile)
    const u16*   W1 = brw ? r1T : w1T;
    const float* B1 = brw ? rb1 : b1a;
    bf16x8 wB[2][4];        // [ct][ks] GEMM2 weights for this wave's branch
    float  bz1[2];
    #pragma unroll
    for (int ct = 0; ct < 2; ++ct) {
        #pragma unroll
        for (int ks = 0; ks < 4; ++ks)
            wB[ct][ks] = *reinterpret_cast<const bf16x8*>(W1 + (ct * 16 + m) * 128 + ks * 32 + q * 8);
        bz1[ct] = B1[ct * 16 + m];
    }

    // ---- x staging geometry: thread -> rows {sr, sr+16}, float4 col sc4 ----
    const int sr = tid >> 4, sc4 = tid & 15;
    const float* xb = x + (row0 + sr) * 64 + sc4 * 4;

    // ---- prologue: tile 0 load+commit, tile 1 issue ----
    {
        float4 v0 = *reinterpret_cast<const float4*>(xb);
        float4 v1 = *reinterpret_cast<const float4*>(xb + 1024);
        ushort4 p0, p1;
        p0.x = f2bf(v0.x); p0.y = f2bf(v0.y); p0.z = f2bf(v0.z); p0.w = f2bf(v0.w);
        p1.x = f2bf(v1.x); p1.y = f2bf(v1.y); p1.z = f2bf(v1.z); p1.w = f2bf(v1.w);
        *reinterpret_cast<ushort4*>(&xs[0][sr * XS_LD + sc4 * 4]) = p0;
        *reinterpret_cast<ushort4*>(&xs[0][(sr + 16) * XS_LD + sc4 * 4]) = p1;
        if (tid < ROWS_PB) s_ids[0][tid] = seg_ids[row0 + tid];
    }
    float4 xr0 = *reinterpret_cast<const float4*>(xb + 2048);
    float4 xr1 = *reinterpret_cast<const float4*>(xb + 2048 + 1024);
    int idr = 0;
    if (tid < ROWS_PB) idr = seg_ids[row0 + ROWS_PB + tid];
    __syncthreads();

    int cur = 0;
    #pragma unroll 1
    for (int t = 0; t < TILES_PB; ++t) {
        // ---- Phase A: commit t+1 to LDS, issue t+2, GEMM1 both branches ----
        if (t + 1 < TILES_PB) {
            ushort4 p0, p1;
            p0.x = f2bf(xr0.x); p0.y = f2bf(xr0.y); p0.z = f2bf(xr0.z); p0.w = f2bf(xr0.w);
            p1.x = f2bf(xr1.x); p1.y = f2bf(xr1.y); p1.z = f2bf(xr1.z); p1.w = f2bf(xr1.w);
            *reinterpret_cast<ushort4*>(&xs[cur ^ 1][sr * XS_LD + sc4 * 4]) = p0;
            *reinterpret_cast<ushort4*>(&xs[cur ^ 1][(sr + 16) * XS_LD + sc4 * 4]) = p1;
            if (tid < ROWS_PB) s_ids[cur ^ 1][tid] = idr;
        }
        if (t + 2 < TILES_PB) {
            const float* px = xb + (size_t)(t + 2) * 2048;
            xr0 = *reinterpret_cast<const float4*>(px);
            xr1 = *reinterpret_cast<const float4*>(px + 1024);
            if (tid < ROWS_PB) idr = seg_ids[row0 + (size_t)(t + 2) * ROWS_PB + tid];
        }
        #pragma unroll
        for (int rt = 0; rt < 2; ++rt) {
            bf16x8 a0 = *reinterpret_cast<const bf16x8*>(&xs[cur][(rt * 16 + m) * XS_LD + q * 8]);
            bf16x8 a1 = *reinterpret_cast<const bf16x8*>(&xs[cur][(rt * 16 + m) * XS_LD + 32 + q * 8]);
            #pragma unroll
            for (int br = 0; br < 2; ++br) {
                #pragma unroll
                for (int ct = 0; ct < 2; ++ct) {
                    float b = bz0[br][ct];
                    f32x4 acc = {b, b, b, b};
                    acc = __builtin_amdgcn_mfma_f32_16x16x32_bf16(a0, wA[br][ct][0], acc, 0, 0, 0);
                    acc = __builtin_amdgcn_mfma_f32_16x16x32_bf16(a1, wA[br][ct][1], acc, 0, 0, 0);
                    int colg = br * 128 + (2 * wid + ct) * 16 + m;
                    #pragma unroll
                    for (int i = 0; i < 4; ++i)
                        h1s[(rt * 16 + q * 4 + i) * H1B_LD + colg] = f2bf(fmaxf(acc[i], 0.f));
                }
            }
        }
        __syncthreads();

        // ---- Phase B: GEMM2 both branches (wave -> brw, rtw; ct loop) ----
        {
            bf16x8 a[4];
            #pragma unroll
            for (int ks = 0; ks < 4; ++ks)
                a[ks] = *reinterpret_cast<const bf16x8*>(
                    &h1s[(rtw * 16 + m) * H1B_LD + brw * 128 + ks * 32 + q * 8]);
            #pragma unroll
            for (int ct = 0; ct < 2; ++ct) {
                float b = bz1[ct];
                f32x4 acc = {b, b, b, b};
                #pragma unroll
                for (int ks = 0; ks < 4; ++ks)
                    acc = __builtin_amdgcn_mfma_f32_16x16x32_bf16(a[ks], wB[ct][ks], acc, 0, 0, 0);
                int colg = brw * 32 + ct * 16 + m;
                #pragma unroll
                for (int i = 0; i < 4; ++i)
                    h2s[(rtw * 16 + q * 4 + i) * H2B_LD + colg] = fmaxf(acc[i], 0.f);
            }
        }
        __syncthreads();

        // ---- Phase C: sorted-run segment accumulate ----
        {
            int c = tid & 63, g = tid >> 6;
            float* sp  = (c < 32) ? seg_out : rseg_out;
            int    col = c & 31;
            const int* ids = s_ids[cur];
            if (ids[0] == ids[ROWS_PB - 1]) {
                // whole tile one segment -> block-combine, 1 atomic/col
                float a = 0.f;
                #pragma unroll
                for (int r = 0; r < 8; ++r)
                    a += h2s[(g * 8 + r) * H2B_LD + c];
                sred[g * 64 + c] = a;
                __syncthreads();
                if (g == 0) {
                    float tt = sred[c] + sred[64 + c] + sred[128 + c] + sred[192 + c];
                    atomicAdd(&sp[ids[0] * 32 + col], tt);
                }
            } else {
                int curid = -1; float acc = 0.f;
                #pragma unroll
                for (int r = 0; r < 8; ++r) {
                    int rr = g * 8 + r;
                    int id = ids[rr];
                    if (id != curid) {
                        if (curid >= 0) atomicAdd(&sp[curid * 32 + col], acc);
                        curid = id; acc = 0.f;
                    }
                    acc += h2s[rr * H2B_LD + c];
                }
                if (curid >= 0) atomicAdd(&sp[curid * 32 + col], acc);
            }
        }
        __syncthreads();
        cur ^= 1;
    }
}

// ---------------- per-segment heads + cost MLP + policy (fp32 in, fp32 out) ----------------
__global__ __launch_bounds__(256) void heads_kernel(
    const float* __restrict__ seg, const float* __restrict__ rseg,
    const float* __restrict__ fwd0_w, const float* __restrict__ fwd0_b,
    const float* __restrict__ fwd1_w, const float* __restrict__ fwd1_b,
    const float* __restrict__ com0_w, const float* __restrict__ com0_b,
    const float* __restrict__ com1_w, const float* __restrict__ com1_b,
    const float* __restrict__ bwd0_w, const float* __restrict__ bwd0_b,
    const float* __restrict__ bwd1_w, const float* __restrict__ bwd1_b,
    const float* __restrict__ cost0_w, const float* __restrict__ cost0_b,
    const float* __restrict__ cost1_w, const float* __restrict__ cost1_b,
    const float* __restrict__ pol_w, const float* __restrict__ pol_b,
    float* __restrict__ out)
{
    __shared__ float s_seg[4][32];
    __shared__ float s_rseg[4][32];
    __shared__ float s_c0[4][64];
    const int tid = threadIdx.x, wid = tid >> 6, lane = tid & 63;
    const int s = blockIdx.x * 4 + wid;

    if (lane < 32) {
        s_seg[wid][lane]  = seg[s * 32 + lane];
        s_rseg[wid][lane] = rseg[s * 32 + lane];
    }
    __syncthreads();

    const float* w0s[3] = {fwd0_w, com0_w, bwd0_w};
    const float* b0s[3] = {fwd0_b, com0_b, bwd0_b};
    const float* w1s[3] = {fwd1_w, com1_w, bwd1_w};
    const float* b1s[3] = {fwd1_b, com1_b, bwd1_b};
    float costs[3];
    #pragma unroll
    for (int hh = 0; hh < 3; ++hh) {
        float t = 0.f;
        #pragma unroll
        for (int k = 0; k < 32; ++k)
            t = fmaf(s_seg[wid][k], w0s[hh][k * 64 + lane], t);
        t = fmaxf(t + b0s[hh][lane], 0.f);
        float red = t * w1s[hh][lane];
        red += __shfl_down(red, 32);
        red += __shfl_down(red, 16);
        red += __shfl_down(red, 8);
        red += __shfl_down(red, 4);
        red += __shfl_down(red, 2);
        red += __shfl_down(red, 1);
        costs[hh] = __shfl(red, 0) + b1s[hh][0];
    }

    float c0 = costs[0] * cost0_w[lane] +
               costs[1] * cost0_w[64 + lane] +
               costs[2] * cost0_w[128 + lane] + cost0_b[lane];
    c0 = fmaxf(c0, 0.f);
    s_c0[wid][lane] = c0;
    __syncthreads();

    int kk = lane & 31;
    float c1 = 0.f;
    #pragma unroll 8
    for (int j = 0; j < 64; ++j)
        c1 = fmaf(s_c0[wid][j], cost1_w[j * 32 + kk], c1);
    c1 = fmaxf(c1 + cost1_b[kk], 0.f);

    float p = 0.f;
    if (lane < 32)
        p = s_rseg[wid][lane] * pol_w[lane] + c1 * pol_w[32 + lane];
    p += __shfl_down(p, 32);
    p += __shfl_down(p, 16);
    p += __shfl_down(p, 8);
    p += __shfl_down(p, 4);
    p += __shfl_down(p, 2);
    p += __shfl_down(p, 1);
    if (lane == 0) out[s] = p + pol_b[0];    // fp32 output
}

extern "C" void kernel_launch(void* const* d_in, const int* in_sizes, int n_in,
                              void* d_out, int out_size, void* d_ws, size_t ws_size,
                              hipStream_t stream) {
    const float* x       = (const float*)d_in[0];
    const int*   seg_ids = (const int*)d_in[1];
    const float* tfc0_w = (const float*)d_in[4];
    const float* tfc0_b = (const float*)d_in[5];
    const float* tfc1_w = (const float*)d_in[6];
    const float* tfc1_b = (const float*)d_in[7];
    const float* fwd0_w = (const float*)d_in[8];
    const float* fwd0_b = (const float*)d_in[9];
    const float* fwd1_w = (const float*)d_in[10];
    const float* fwd1_b = (const float*)d_in[11];
    const float* com0_w = (const float*)d_in[12];
    const float* com0_b = (const float*)d_in[13];
    const float* com1_w = (const float*)d_in[14];
    const float* com1_b = (const float*)d_in[15];
    const float* bwd0_w = (const float*)d_in[16];
    const float* bwd0_b = (const float*)d_in[17];
    const float* bwd1_w = (const float*)d_in[18];
    const float* bwd1_b = (const float*)d_in[19];
    const float* rl0_w  = (const float*)d_in[20];
    const float* rl0_b  = (const float*)d_in[21];
    const float* rl1_w  = (const float*)d_in[22];
    const float* rl1_b  = (const float*)d_in[23];
    const float* cost0_w = (const float*)d_in[24];
    const float* cost0_b = (const float*)d_in[25];
    const float* cost1_w = (const float*)d_in[26];
    const float* cost1_b = (const float*)d_in[27];
    const float* pol_w   = (const float*)d_in[28];
    const float* pol_b   = (const float*)d_in[29];

    char* ws = (char*)d_ws;
    const size_t seg_bytes = (size_t)S_SEG * 32 * sizeof(float);   // 2 MB each
    float* seg  = (float*)ws;
    float* rseg = (float*)(ws + seg_bytes);
    u16* w0T = (u16*)(ws + 2 * seg_bytes);
    u16* w1T = w0T + 128 * 64;
    u16* r0T = w1T + 32 * 128;
    u16* r1T = r0T + 128 * 64;

    int n4 = (int)(2 * seg_bytes / 16);
    zero_ws_kernel<<<(n4 + 255) / 256, 256, 0, stream>>>(seg, n4);
    transpose_weights<<<96, 256, 0, stream>>>(tfc0_w, tfc1_w, rl0_w, rl1_w,
                                              w0T, w1T, r0T, r1T);
    main_mlp_seg<<<GRID_MAIN, 256, 0, stream>>>(
        x, seg_ids, w0T, tfc0_b, w1T, tfc1_b, r0T, rl0_b, r1T, rl1_b, seg, rseg);
    heads_kernel<<<S_SEG / 4, 256, 0, stream>>>(
        seg, rseg,
        fwd0_w, fwd0_b, fwd1_w, fwd1_b,
        com0_w, com0_b, com1_w, com1_b,
        bwd0_w, bwd0_b, bwd1_w, bwd1_b,
        cost0_w, cost0_b, cost1_w, cost1_b,
        pol_w, pol_b, (float*)d_out);
}